// Round 14
// baseline (673.620 us; speedup 1.0000x reference)
//
#include <hip/hip_runtime.h>
#include <hip/hip_bf16.h>
#include <stdint.h>

#define DIM 512
#define INNER 1344
#define INNERP 1408

typedef __attribute__((ext_vector_type(8))) short vbf8;
typedef __attribute__((ext_vector_type(4))) float vf4;
typedef __attribute__((ext_vector_type(2))) float vf2;
typedef __attribute__((ext_vector_type(4))) int v4i;
typedef __attribute__((ext_vector_type(8))) int v8i;

typedef __attribute__((address_space(1))) void as1void;
typedef __attribute__((address_space(3))) void as3void;

union frag8 {
  v8i w;
  v4i h[2];
};

__device__ __forceinline__ unsigned pk4fp8(float a, float b, float c, float d) {
  int v = __builtin_amdgcn_cvt_pk_fp8_f32(a, b, 0, false);
  v = __builtin_amdgcn_cvt_pk_fp8_f32(c, d, v, true);
  return (unsigned)v;
}
__device__ __forceinline__ uint8_t q8(float v) {
  return (uint8_t)(__builtin_amdgcn_cvt_pk_fp8_f32(v, v, 0, false) & 0xff);
}
// 8 fp8 bytes -> 8 bf16 (in-register, fp8 e4m3 OCP)
__device__ __forceinline__ vbf8 cvt8fp8(uint2 wv) {
  union {
    vbf8 v;
    __hip_bfloat16 e[8];
  } o;
  vf2 f;
  f = __builtin_amdgcn_cvt_pk_f32_fp8((int)wv.x, false);
  o.e[0] = __float2bfloat16(f.x);
  o.e[1] = __float2bfloat16(f.y);
  f = __builtin_amdgcn_cvt_pk_f32_fp8((int)wv.x, true);
  o.e[2] = __float2bfloat16(f.x);
  o.e[3] = __float2bfloat16(f.y);
  f = __builtin_amdgcn_cvt_pk_f32_fp8((int)wv.y, false);
  o.e[4] = __float2bfloat16(f.x);
  o.e[5] = __float2bfloat16(f.y);
  f = __builtin_amdgcn_cvt_pk_f32_fp8((int)wv.y, true);
  o.e[6] = __float2bfloat16(f.x);
  o.e[7] = __float2bfloat16(f.y);
  return o.v;
}

// fp8 x fp8, unit scales (R5-validated call form).
#define MFMA_SC(a, b, c) \
  __builtin_amdgcn_mfma_scale_f32_16x16x128_f8f6f4((a), (b), (c), 0, 0, 0, 127, 0, 127)

// ---------------- weight transpose + fp8 cast: WT[n'][k] = W[k][n] ----------------
__global__ void k_transpose(const float* __restrict__ Wsrc, uint8_t* __restrict__ WT,
                            int K, int N, int ldOut, int nsplit) {
  __shared__ float tile[32][33];
  const int tx = threadIdx.x, ty = threadIdx.y;
  const int n0 = blockIdx.x * 32, k0 = blockIdx.y * 32;
#pragma unroll
  for (int i = 0; i < 32; i += 8) {
    int k = k0 + ty + i, n = n0 + tx;
    if (k < K && n < N) tile[ty + i][tx] = Wsrc[(size_t)k * N + n];
  }
  __syncthreads();
#pragma unroll
  for (int i = 0; i < 32; i += 8) {
    int n = n0 + ty + i, k = k0 + tx;
    if (n < N && k < K) {
      int np = n + (n >= nsplit ? 64 : 0);
      WT[(size_t)np * ldOut + k] = q8(tile[tx][ty + i]);
    }
  }
}

// ---------------- pad GLU bias into [2816] ----------------
__global__ void k_padbias(const float* __restrict__ b, float* __restrict__ o) {
  int c = blockIdx.x * 256 + threadIdx.x;
  if (c < INNER) o[c] = b[c];
  else if (c >= INNERP && c < INNERP + INNER) o[c] = b[c - 64];
  else if (c < 2816) o[c] = 0.0f;
}

// ---------------- LayerNorm (+ optional window partition) -> fp8 ----------------
template <bool PART, bool BF16IN>
__global__ __launch_bounds__(256) void k_ln(const void* __restrict__ xin,
                                            const float* __restrict__ gw,
                                            const float* __restrict__ bw,
                                            uint8_t* __restrict__ y) {
  const int wave = threadIdx.x >> 6, lane = threadIdx.x & 63;
  const int tok = blockIdx.x * 4 + wave;
  float vals[8];
  if (BF16IN) {
    const __hip_bfloat16* xr = (const __hip_bfloat16*)xin + (size_t)tok * DIM + lane * 8;
    union {
      vbf8 v;
      ushort e[8];
    } u;
    u.v = *(const vbf8*)xr;
#pragma unroll
    for (int j = 0; j < 8; ++j) vals[j] = __uint_as_float((unsigned)u.e[j] << 16);
  } else {
    const float* xr = (const float*)xin + (size_t)tok * DIM + lane * 8;
    const float4 v0 = *(const float4*)xr;
    const float4 v1 = *(const float4*)(xr + 4);
    vals[0] = v0.x; vals[1] = v0.y; vals[2] = v0.z; vals[3] = v0.w;
    vals[4] = v1.x; vals[5] = v1.y; vals[6] = v1.z; vals[7] = v1.w;
  }
  float s = 0.f, ss = 0.f;
#pragma unroll
  for (int j = 0; j < 8; ++j) {
    s += vals[j];
    ss += vals[j] * vals[j];
  }
#pragma unroll
  for (int off = 32; off > 0; off >>= 1) {
    s += __shfl_xor(s, off);
    ss += __shfl_xor(ss, off);
  }
  const float mu = s * (1.0f / DIM);
  const float rs = rsqrtf(ss * (1.0f / DIM) - mu * mu + 1e-6f);
  size_t orow;
  if (PART) {
    int b = tok / 9216, rem = tok % 9216;
    int h = rem / 96, w = rem % 96;
    orow = (size_t)(((b * 12 + (h >> 3)) * 12 + (w >> 3)) * 64 + (h & 7) * 8 + (w & 7));
  } else {
    orow = (size_t)tok;
  }
  const float4 g0 = *(const float4*)(gw + lane * 8);
  const float4 g1 = *(const float4*)(gw + lane * 8 + 4);
  const float4 b0 = *(const float4*)(bw + lane * 8);
  const float4 b1 = *(const float4*)(bw + lane * 8 + 4);
  const float gg[8] = {g0.x, g0.y, g0.z, g0.w, g1.x, g1.y, g1.z, g1.w};
  const float bb[8] = {b0.x, b0.y, b0.z, b0.w, b1.x, b1.y, b1.z, b1.w};
  float r[8];
#pragma unroll
  for (int j = 0; j < 8; ++j) r[j] = (vals[j] - mu) * rs * gg[j] + bb[j];
  uint2 po;
  po.x = pk4fp8(r[0], r[1], r[2], r[3]);
  po.y = pk4fp8(r[4], r[5], r[6], r[7]);
  *(uint2*)(y + orow * DIM + lane * 8) = po;
}

// ---------------- 256x128 fp8 GEMM: 8 waves (4M x 2N), single-buffer 2-phase ----------
// Per-wave structure identical to R11 (acc[4][4], 16 ds_reads/tile). LDS 48KB.
// MODE 0: fp8 out = acc + bias                              (QKV)
// MODE 1: window-reverse; bf16 out = f32resid + ls*(acc+b)  (proj -> x1b)
// MODE 2: f32 out = bf16resid + ls*(acc+b)                  (fc2 -> d_out)
template <int K, int MODE, int NT>
__global__ __launch_bounds__(512, 4) void k_gemm256(const uint8_t* __restrict__ A8,
                                                    const uint8_t* __restrict__ W8,
                                                    const float* __restrict__ bias,
                                                    void* __restrict__ outp,
                                                    const void* __restrict__ resid,
                                                    const float* __restrict__ lsv,
                                                    const int ldOut) {
  __shared__ alignas(16) char As[256 * 128];
  __shared__ alignas(16) char Ws[128 * 128];
  const int nwg = gridDim.x;
  int bid = blockIdx.x;
  bid = (bid & 7) * (nwg >> 3) + (bid >> 3);  // bijective XCD swizzle (nwg%8==0)
  const int bm = bid / NT, bn = bid % NT;
  const int tid = threadIdx.x, wave = tid >> 6, lane = tid & 63;
  const int wr = wave >> 1, wc = wave & 1;
  const int cl = lane & 15, g = lane >> 4;
  constexpr int nkt = K >> 7;

  const int ro = lane >> 3, pb = lane & 7;
  const int swz = (pb ^ ro) << 4;
  const int r0a = wave * 32;   // A: 256 rows / 8 waves
  const int r0w = wave * 16;   // W: 128 rows / 8 waves
  const uint8_t* asrc = A8 + (size_t)bm * 256 * K + (size_t)(r0a + ro) * K + swz;
  const uint8_t* wsrc = W8 + (size_t)bn * 128 * K + (size_t)(r0w + ro) * K + swz;
  char* adst = As + r0a * 128;
  char* wdst = Ws + r0w * 128;

  int aoff[4][2], woff[4][2];
#pragma unroll
  for (int i = 0; i < 4; ++i) {
    const int ra = wr * 64 + cl + i * 16;
    const int rb = wc * 64 + cl + i * 16;
    aoff[i][0] = ra * 128 + (((2 * g) ^ (ra & 7)) << 4);
    aoff[i][1] = ra * 128 + (((2 * g + 1) ^ (ra & 7)) << 4);
    woff[i][0] = rb * 128 + (((2 * g) ^ (rb & 7)) << 4);
    woff[i][1] = rb * 128 + (((2 * g + 1) ^ (rb & 7)) << 4);
  }

  vf4 acc[4][4] = {};

  for (int t = 0; t < nkt; ++t) {
    __syncthreads();
#pragma unroll
    for (int c = 0; c < 32; c += 8)
      __builtin_amdgcn_global_load_lds((const as1void*)(asrc + (size_t)c * K),
                                       (as3void*)(adst + c * 128), 16, 0, 0);
#pragma unroll
    for (int c = 0; c < 16; c += 8)
      __builtin_amdgcn_global_load_lds((const as1void*)(wsrc + (size_t)c * K),
                                       (as3void*)(wdst + c * 128), 16, 0, 0);
    asrc += 128;
    wsrc += 128;
    __syncthreads();
    frag8 af[4], wf[4];
#pragma unroll
    for (int i = 0; i < 4; ++i) {
      af[i].h[0] = *(const v4i*)(As + aoff[i][0]);
      af[i].h[1] = *(const v4i*)(As + aoff[i][1]);
      wf[i].h[0] = *(const v4i*)(Ws + woff[i][0]);
      wf[i].h[1] = *(const v4i*)(Ws + woff[i][1]);
    }
#pragma unroll
    for (int mi = 0; mi < 4; ++mi)
#pragma unroll
      for (int ni = 0; ni < 4; ++ni)
        acc[mi][ni] = MFMA_SC(af[mi].w, wf[ni].w, acc[mi][ni]);
  }

  const int rl = g << 2;
  const int rbase = bm * 256 + wr * 64;
  const int cbase = bn * 128 + wc * 64;
#pragma unroll
  for (int mi = 0; mi < 4; ++mi) {
#pragma unroll
    for (int j = 0; j < 4; ++j) {
      const int r = rbase + mi * 16 + rl + j;
      size_t orow;
      if (MODE == 1) {
        int m = r >> 6, t2 = r & 63;
        int b = m / 144, mm = m % 144;
        int wh = mm / 12, ww = mm % 12;
        int h = wh * 8 + (t2 >> 3), w = ww * 8 + (t2 & 7);
        orow = (size_t)((b * 96 + h) * 96 + w);
      } else {
        orow = (size_t)r;
      }
#pragma unroll
      for (int ni = 0; ni < 4; ++ni) {
        const int c = cbase + ni * 16 + cl;
        const float v = acc[mi][ni][j] + bias[c];
        if (MODE == 0) {
          ((uint8_t*)outp)[(size_t)r * ldOut + c] = q8(v);
        } else if (MODE == 1) {
          const float* rx = (const float*)resid;
          ((__hip_bfloat16*)outp)[orow * DIM + c] =
              __float2bfloat16(rx[orow * DIM + c] + lsv[c] * v);
        } else {
          const __hip_bfloat16* rx = (const __hip_bfloat16*)resid;
          ((float*)outp)[(size_t)r * DIM + c] =
              __bfloat162float(rx[(size_t)r * DIM + c]) + lsv[c] * v;
        }
      }
    }
  }
}

// ---------------- GLU fp8 GEMM: 256-row blocks, 8 waves, fp8 h out --------------
__global__ __launch_bounds__(512, 4) void k_gemm_glu(const uint8_t* __restrict__ A8,
                                                     const uint8_t* __restrict__ W8,
                                                     const float* __restrict__ bias,
                                                     uint8_t* __restrict__ hout) {
  __shared__ alignas(16) char As[256 * 128];
  __shared__ alignas(16) char B0s[64 * 128];
  __shared__ alignas(16) char B1s[64 * 128];
  constexpr int K = DIM;
  const int nwg = gridDim.x;
  int bid = blockIdx.x;
  bid = (bid & 7) * (nwg >> 3) + (bid >> 3);
  const int bm = bid / 22, bn = bid % 22;
  const int tid = threadIdx.x, wave = tid >> 6, lane = tid & 63;
  const int wr = wave >> 1, wc = wave & 1;
  const int cl = lane & 15, g = lane >> 4;

  const int ro = lane >> 3, pb = lane & 7;
  const int swz = (pb ^ ro) << 4;
  const int r0a = wave * 32, r0b = wave * 8;
  const uint8_t* asrc = A8 + (size_t)bm * 256 * K + (size_t)(r0a + ro) * K + swz;
  const uint8_t* b0src = W8 + (size_t)(bn * 64 + r0b + ro) * K + swz;
  const uint8_t* b1src = W8 + (size_t)(INNERP + bn * 64 + r0b + ro) * K + swz;
  char* adst = As + r0a * 128;
  char* b0dst = B0s + r0b * 128;
  char* b1dst = B1s + r0b * 128;

  int aoff[4][2], boff[2][2];
#pragma unroll
  for (int i = 0; i < 4; ++i) {
    const int ra = wr * 64 + cl + i * 16;
    aoff[i][0] = ra * 128 + (((2 * g) ^ (ra & 7)) << 4);
    aoff[i][1] = ra * 128 + (((2 * g + 1) ^ (ra & 7)) << 4);
  }
#pragma unroll
  for (int i = 0; i < 2; ++i) {
    const int rb = wc * 32 + cl + i * 16;
    boff[i][0] = rb * 128 + (((2 * g) ^ (rb & 7)) << 4);
    boff[i][1] = rb * 128 + (((2 * g + 1) ^ (rb & 7)) << 4);
  }

  vf4 a0[4][2] = {}, a1[4][2] = {};

#pragma unroll
  for (int t = 0; t < 4; ++t) {
    __syncthreads();
#pragma unroll
    for (int c = 0; c < 32; c += 8)
      __builtin_amdgcn_global_load_lds((const as1void*)(asrc + (size_t)c * K),
                                       (as3void*)(adst + c * 128), 16, 0, 0);
    __builtin_amdgcn_global_load_lds((const as1void*)b0src, (as3void*)b0dst, 16, 0, 0);
    __builtin_amdgcn_global_load_lds((const as1void*)b1src, (as3void*)b1dst, 16, 0, 0);
    asrc += 128;
    b0src += 128;
    b1src += 128;
    __syncthreads();
    frag8 af[4], w0f[2], w1f[2];
#pragma unroll
    for (int i = 0; i < 4; ++i) {
      af[i].h[0] = *(const v4i*)(As + aoff[i][0]);
      af[i].h[1] = *(const v4i*)(As + aoff[i][1]);
    }
#pragma unroll
    for (int i = 0; i < 2; ++i) {
      w0f[i].h[0] = *(const v4i*)(B0s + boff[i][0]);
      w0f[i].h[1] = *(const v4i*)(B0s + boff[i][1]);
      w1f[i].h[0] = *(const v4i*)(B1s + boff[i][0]);
      w1f[i].h[1] = *(const v4i*)(B1s + boff[i][1]);
    }
#pragma unroll
    for (int mi = 0; mi < 4; ++mi)
#pragma unroll
      for (int ni = 0; ni < 2; ++ni) {
        a0[mi][ni] = MFMA_SC(af[mi].w, w0f[ni].w, a0[mi][ni]);
        a1[mi][ni] = MFMA_SC(af[mi].w, w1f[ni].w, a1[mi][ni]);
      }
  }

  const int rl = g << 2;
  const int rbase = bm * 256 + wr * 64;
  const int cbase = bn * 64 + wc * 32;
#pragma unroll
  for (int mi = 0; mi < 4; ++mi)
#pragma unroll
    for (int j = 0; j < 4; ++j) {
      const int r = rbase + mi * 16 + rl + j;
#pragma unroll
      for (int ni = 0; ni < 2; ++ni) {
        const int c = cbase + ni * 16 + cl;
        const float a = a0[mi][ni][j] + bias[c];
        const float gv = a1[mi][ni][j] + bias[INNERP + c];
        const float sg = 1.0f / (1.0f + __expf(-gv));
        hout[(size_t)r * INNERP + c] = q8(a * gv * sg);
      }
    }
}

// ---------------- attention: bf16 MFMA core, fp8 in (reg convert) / fp8 out -----------
__global__ __launch_bounds__(256, 2) void k_attn_mfma(const uint8_t* __restrict__ qkv,
                                                      uint8_t* __restrict__ o) {
  __shared__ __hip_bfloat16 sm[4][6912];
  const int wave = threadIdx.x >> 6, lane = threadIdx.x & 63;
  const int task = blockIdx.x * 4 + wave;
  const int w = task >> 4, hd = task & 15;
  const int g = lane >> 4, c = lane & 15;
  __hip_bfloat16* smp = sm[wave];
  __hip_bfloat16* smv = smp + 4608;

  const uint8_t* base = qkv + (size_t)w * 64 * 1536 + hd * 32;

  vbf8 qf[4], kf[4];
#pragma unroll
  for (int i = 0; i < 4; ++i) {
    const uint8_t* qrow = base + (size_t)(i * 16 + c) * 1536 + g * 8;
    qf[i] = cvt8fp8(*(const uint2*)qrow);
    kf[i] = cvt8fp8(*(const uint2*)(qrow + 512));
  }

  {
    const uint8_t* vrow = base + (size_t)lane * 1536 + 1024;
    union {
      vbf8 v;
      ushort e[8];
    } uv;
#pragma unroll
    for (int i = 0; i < 4; ++i) {
      uv.v = cvt8fp8(*(const uint2*)(vrow + i * 8));
#pragma unroll
      for (int j = 0; j < 8; ++j)
        ((ushort*)smv)[(i * 8 + j) * 72 + lane] = uv.e[j];
    }
  }

  vf4 st[4][4];
#pragma unroll
  for (int iq = 0; iq < 4; ++iq)
#pragma unroll
    for (int it = 0; it < 4; ++it) {
      vf4 z = {};
      st[iq][it] = __builtin_amdgcn_mfma_f32_16x16x32_bf16(qf[iq], kf[it], z, 0, 0, 0);
    }

  float inv[4][4];
#pragma unroll
  for (int iq = 0; iq < 4; ++iq) {
#pragma unroll
    for (int j = 0; j < 4; ++j) {
      float m = fmaxf(fmaxf(st[iq][0][j], st[iq][1][j]), fmaxf(st[iq][2][j], st[iq][3][j]));
      m = fmaxf(m, __shfl_xor(m, 1));
      m = fmaxf(m, __shfl_xor(m, 2));
      m = fmaxf(m, __shfl_xor(m, 4));
      m = fmaxf(m, __shfl_xor(m, 8));
      float s = 0.f;
#pragma unroll
      for (int it = 0; it < 4; ++it) {
        const float e = __expf((st[iq][it][j] - m) * 0.17677669529663687f);
        st[iq][it][j] = e;
        s += e;
      }
      s += __shfl_xor(s, 1);
      s += __shfl_xor(s, 2);
      s += __shfl_xor(s, 4);
      s += __shfl_xor(s, 8);
      inv[iq][j] = 1.0f / s;
    }
  }

#pragma unroll
  for (int iq = 0; iq < 4; ++iq)
#pragma unroll
    for (int j = 0; j < 4; ++j) {
      const int q = iq * 16 + g * 4 + j;
#pragma unroll
      for (int it = 0; it < 4; ++it)
        smp[q * 72 + it * 16 + c] = __float2bfloat16(st[iq][it][j]);
    }

  vf4 ot[4][2] = {};
#pragma unroll
  for (int ks = 0; ks < 2; ++ks) {
    vbf8 pf[4], vfr[2];
#pragma unroll
    for (int iq = 0; iq < 4; ++iq)
      pf[iq] = *(const vbf8*)(smp + (iq * 16 + c) * 72 + ks * 32 + g * 8);
#pragma unroll
    for (int dt = 0; dt < 2; ++dt)
      vfr[dt] = *(const vbf8*)(smv + (dt * 16 + c) * 72 + ks * 32 + g * 8);
#pragma unroll
    for (int iq = 0; iq < 4; ++iq)
#pragma unroll
      for (int dt = 0; dt < 2; ++dt)
        ot[iq][dt] = __builtin_amdgcn_mfma_f32_16x16x32_bf16(pf[iq], vfr[dt], ot[iq][dt], 0, 0, 0);
  }

#pragma unroll
  for (int iq = 0; iq < 4; ++iq)
#pragma unroll
    for (int dt = 0; dt < 2; ++dt)
#pragma unroll
      for (int j = 0; j < 4; ++j) {
        const int q = iq * 16 + g * 4 + j;
        smp[q * 72 + dt * 16 + c] = __float2bfloat16(ot[iq][dt][j] * inv[iq][j]);
      }
  uint8_t* ob = o + (size_t)w * 64 * 512 + hd * 32;
#pragma unroll
  for (int i = 0; i < 4; ++i) {
    const int idx = i * 64 + lane;
    const int row = idx >> 2, chunk = idx & 3;
    union {
      vbf8 v;
      ushort e[8];
    } u;
    u.v = *(const vbf8*)(smp + row * 72 + chunk * 8);
    float f[8];
#pragma unroll
    for (int j = 0; j < 8; ++j) f[j] = __uint_as_float((unsigned)u.e[j] << 16);
    uint2 pv;
    pv.x = pk4fp8(f[0], f[1], f[2], f[3]);
    pv.y = pk4fp8(f[4], f[5], f[6], f[7]);
    *(uint2*)(ob + (size_t)row * 512 + chunk * 8) = pv;
  }
}

// ---------------- launch ----------------
extern "C" void kernel_launch(void* const* d_in, const int* in_sizes, int n_in, void* d_out,
                              int out_size, void* d_ws, size_t ws_size, hipStream_t stream) {
  const float* x = (const float*)d_in[0];
  const float* n1g = (const float*)d_in[1];
  const float* n1b = (const float*)d_in[2];
  const float* qkv_w = (const float*)d_in[3];
  const float* qkv_b = (const float*)d_in[4];
  const float* proj_w = (const float*)d_in[5];
  const float* proj_b = (const float*)d_in[6];
  const float* ls1 = (const float*)d_in[7];
  const float* n2g = (const float*)d_in[8];
  const float* n2b = (const float*)d_in[9];
  const float* glu_w = (const float*)d_in[10];
  const float* glu_b = (const float*)d_in[11];
  const float* fc2_w = (const float*)d_in[12];
  const float* fc2_b = (const float*)d_in[13];
  const float* ls2 = (const float*)d_in[14];

  if (ws_size < 268000000u) return;

  char* ws = (char*)d_ws;
  uint8_t* wTq = (uint8_t*)(ws + 0);            // [1536][512] fp8
  uint8_t* wTp = (uint8_t*)(ws + 786432);       // [512][512]
  uint8_t* wTg = (uint8_t*)(ws + 1048576);      // [2816][512] padded
  uint8_t* wTf = (uint8_t*)(ws + 2490368);      // [512][1408] padded
  float* gbias = (float*)(ws + 3211264);        // [2816]
  uint8_t* act8 = (uint8_t*)(ws + 3222528);     // [73728][512] fp8 (y1 -> o -> y2)
  char* big = ws + 40971264;
  uint8_t* qkv8 = (uint8_t*)big;                // [73728][1536] fp8 (113 MB)
  uint8_t* h8 = (uint8_t*)big;                  // [73728][1408] fp8 (alias, dead qkv)
  __hip_bfloat16* x1b = (__hip_bfloat16*)(big + 113246208);  // [73728][512] bf16

  hipMemsetAsync(wTg, 0, 1441792, stream);
  hipMemsetAsync(wTf, 0, 720896, stream);

  dim3 tb(32, 8);
  k_transpose<<<dim3(48, 16), tb, 0, stream>>>(qkv_w, wTq, 512, 1536, 512, 1 << 30);
  k_transpose<<<dim3(16, 16), tb, 0, stream>>>(proj_w, wTp, 512, 512, 512, 1 << 30);
  k_transpose<<<dim3(84, 16), tb, 0, stream>>>(glu_w, wTg, 512, 2688, 512, INNER);
  k_transpose<<<dim3(16, 42), tb, 0, stream>>>(fc2_w, wTf, 1344, 512, 1408, 1 << 30);
  k_padbias<<<11, 256, 0, stream>>>(glu_b, gbias);

  k_ln<true, false><<<18432, 256, 0, stream>>>(x, n1g, n1b, act8);
  k_gemm256<512, 0, 12><<<3456, 512, 0, stream>>>(act8, wTq, qkv_b, qkv8, nullptr, nullptr, 1536);
  k_attn_mfma<<<4608, 256, 0, stream>>>(qkv8, act8);
  k_gemm256<512, 1, 4><<<1152, 512, 0, stream>>>(act8, wTp, proj_b, (void*)x1b, x, ls1, 512);
  k_ln<false, true><<<18432, 256, 0, stream>>>(x1b, n2g, n2b, act8);
  k_gemm_glu<<<6336, 512, 0, stream>>>(act8, wTg, gbias, h8);
  k_gemm256<1408, 2, 4><<<1152, 512, 0, stream>>>(h8, wTf, fc2_b, d_out, x1b, ls2, 512);
}

// Round 15
// 540.140 us; speedup vs baseline: 1.2471x; 1.2471x over previous
//
#include <hip/hip_runtime.h>
#include <hip/hip_bf16.h>
#include <stdint.h>

#define DIM 512
#define INNER 1344
#define INNERP 1408

typedef __attribute__((ext_vector_type(8))) short vbf8;
typedef __attribute__((ext_vector_type(4))) float vf4;
typedef __attribute__((ext_vector_type(2))) float vf2;
typedef __attribute__((ext_vector_type(4))) int v4i;
typedef __attribute__((ext_vector_type(8))) int v8i;

typedef __attribute__((address_space(1))) void as1void;
typedef __attribute__((address_space(3))) void as3void;

union frag8 {
  v8i w;
  v4i h[2];
};

__device__ __forceinline__ unsigned pk4fp8(float a, float b, float c, float d) {
  int v = __builtin_amdgcn_cvt_pk_fp8_f32(a, b, 0, false);
  v = __builtin_amdgcn_cvt_pk_fp8_f32(c, d, v, true);
  return (unsigned)v;
}
__device__ __forceinline__ uint8_t q8(float v) {
  return (uint8_t)(__builtin_amdgcn_cvt_pk_fp8_f32(v, v, 0, false) & 0xff);
}
// 8 fp8 bytes -> 8 bf16 (in-register, fp8 e4m3 OCP)
__device__ __forceinline__ vbf8 cvt8fp8(uint2 wv) {
  union {
    vbf8 v;
    __hip_bfloat16 e[8];
  } o;
  vf2 f;
  f = __builtin_amdgcn_cvt_pk_f32_fp8((int)wv.x, false);
  o.e[0] = __float2bfloat16(f.x);
  o.e[1] = __float2bfloat16(f.y);
  f = __builtin_amdgcn_cvt_pk_f32_fp8((int)wv.x, true);
  o.e[2] = __float2bfloat16(f.x);
  o.e[3] = __float2bfloat16(f.y);
  f = __builtin_amdgcn_cvt_pk_f32_fp8((int)wv.y, false);
  o.e[4] = __float2bfloat16(f.x);
  o.e[5] = __float2bfloat16(f.y);
  f = __builtin_amdgcn_cvt_pk_f32_fp8((int)wv.y, true);
  o.e[6] = __float2bfloat16(f.x);
  o.e[7] = __float2bfloat16(f.y);
  return o.v;
}

// fp8 x fp8, unit scales (R5-validated call form).
#define MFMA_SC(a, b, c) \
  __builtin_amdgcn_mfma_scale_f32_16x16x128_f8f6f4((a), (b), (c), 0, 0, 0, 127, 0, 127)

// ---------------- weight transpose + fp8 cast: WT[n'][k] = W[k][n] ----------------
__global__ void k_transpose(const float* __restrict__ Wsrc, uint8_t* __restrict__ WT,
                            int K, int N, int ldOut, int nsplit) {
  __shared__ float tile[32][33];
  const int tx = threadIdx.x, ty = threadIdx.y;
  const int n0 = blockIdx.x * 32, k0 = blockIdx.y * 32;
#pragma unroll
  for (int i = 0; i < 32; i += 8) {
    int k = k0 + ty + i, n = n0 + tx;
    if (k < K && n < N) tile[ty + i][tx] = Wsrc[(size_t)k * N + n];
  }
  __syncthreads();
#pragma unroll
  for (int i = 0; i < 32; i += 8) {
    int n = n0 + ty + i, k = k0 + tx;
    if (n < N && k < K) {
      int np = n + (n >= nsplit ? 64 : 0);
      WT[(size_t)np * ldOut + k] = q8(tile[tx][ty + i]);
    }
  }
}

// ---------------- pad GLU bias into [2816] ----------------
__global__ void k_padbias(const float* __restrict__ b, float* __restrict__ o) {
  int c = blockIdx.x * 256 + threadIdx.x;
  if (c < INNER) o[c] = b[c];
  else if (c >= INNERP && c < INNERP + INNER) o[c] = b[c - 64];
  else if (c < 2816) o[c] = 0.0f;
}

// ---------------- LayerNorm (+ optional window partition) -> fp8 ----------------
template <bool PART, bool BF16IN>
__global__ __launch_bounds__(256) void k_ln(const void* __restrict__ xin,
                                            const float* __restrict__ gw,
                                            const float* __restrict__ bw,
                                            uint8_t* __restrict__ y) {
  const int wave = threadIdx.x >> 6, lane = threadIdx.x & 63;
  const int tok = blockIdx.x * 4 + wave;
  float vals[8];
  if (BF16IN) {
    const __hip_bfloat16* xr = (const __hip_bfloat16*)xin + (size_t)tok * DIM + lane * 8;
    union {
      vbf8 v;
      ushort e[8];
    } u;
    u.v = *(const vbf8*)xr;
#pragma unroll
    for (int j = 0; j < 8; ++j) vals[j] = __uint_as_float((unsigned)u.e[j] << 16);
  } else {
    const float* xr = (const float*)xin + (size_t)tok * DIM + lane * 8;
    const float4 v0 = *(const float4*)xr;
    const float4 v1 = *(const float4*)(xr + 4);
    vals[0] = v0.x; vals[1] = v0.y; vals[2] = v0.z; vals[3] = v0.w;
    vals[4] = v1.x; vals[5] = v1.y; vals[6] = v1.z; vals[7] = v1.w;
  }
  float s = 0.f, ss = 0.f;
#pragma unroll
  for (int j = 0; j < 8; ++j) {
    s += vals[j];
    ss += vals[j] * vals[j];
  }
#pragma unroll
  for (int off = 32; off > 0; off >>= 1) {
    s += __shfl_xor(s, off);
    ss += __shfl_xor(ss, off);
  }
  const float mu = s * (1.0f / DIM);
  const float rs = rsqrtf(ss * (1.0f / DIM) - mu * mu + 1e-6f);
  size_t orow;
  if (PART) {
    int b = tok / 9216, rem = tok % 9216;
    int h = rem / 96, w = rem % 96;
    orow = (size_t)(((b * 12 + (h >> 3)) * 12 + (w >> 3)) * 64 + (h & 7) * 8 + (w & 7));
  } else {
    orow = (size_t)tok;
  }
  const float4 g0 = *(const float4*)(gw + lane * 8);
  const float4 g1 = *(const float4*)(gw + lane * 8 + 4);
  const float4 b0 = *(const float4*)(bw + lane * 8);
  const float4 b1 = *(const float4*)(bw + lane * 8 + 4);
  const float gg[8] = {g0.x, g0.y, g0.z, g0.w, g1.x, g1.y, g1.z, g1.w};
  const float bb[8] = {b0.x, b0.y, b0.z, b0.w, b1.x, b1.y, b1.z, b1.w};
  float r[8];
#pragma unroll
  for (int j = 0; j < 8; ++j) r[j] = (vals[j] - mu) * rs * gg[j] + bb[j];
  uint2 po;
  po.x = pk4fp8(r[0], r[1], r[2], r[3]);
  po.y = pk4fp8(r[4], r[5], r[6], r[7]);
  *(uint2*)(y + orow * DIM + lane * 8) = po;
}

// ---------------- 128x128 fp8 GEMM (R11 core: single-buffer, hoisted) ----------------
// MODE 0: fp8 out = acc + bias                              (QKV)
// MODE 1: window-reverse; bf16 out = f32resid + ls*(acc+b)  (proj -> x1b)
// MODE 2: f32 out = bf16resid + ls*(acc+b)                  (fc2 -> d_out)
template <int K, int MODE, int NT>
__global__ __launch_bounds__(256, 2) void k_gemm128(const uint8_t* __restrict__ A8,
                                                    const uint8_t* __restrict__ W8,
                                                    const float* __restrict__ bias,
                                                    void* __restrict__ outp,
                                                    const void* __restrict__ resid,
                                                    const float* __restrict__ lsv,
                                                    const int ldOut) {
  __shared__ alignas(16) char As[128 * 128];
  __shared__ alignas(16) char Ws[128 * 128];
  const int nwg = gridDim.x;
  int bid = blockIdx.x;
  bid = (bid & 7) * (nwg >> 3) + (bid >> 3);  // bijective XCD swizzle (nwg%8==0)
  const int bm = bid / NT, bn = bid % NT;
  const int tid = threadIdx.x, wave = tid >> 6, lane = tid & 63;
  const int wr = wave >> 1, wc = wave & 1;
  const int cl = lane & 15, g = lane >> 4;
  constexpr int nkt = K >> 7;

  const int r0 = wave * 32;
  const int ro = lane >> 3, pb = lane & 7;
  const int swz = (pb ^ ro) << 4;
  const uint8_t* asrc = A8 + (size_t)bm * 128 * K + (size_t)(r0 + ro) * K + swz;
  const uint8_t* wsrc = W8 + (size_t)bn * 128 * K + (size_t)(r0 + ro) * K + swz;
  char* adst = As + r0 * 128;
  char* wdst = Ws + r0 * 128;

  int aoff[4][2], woff[4][2];
#pragma unroll
  for (int i = 0; i < 4; ++i) {
    const int ra = wr * 64 + cl + i * 16;
    const int rb = wc * 64 + cl + i * 16;
    aoff[i][0] = ra * 128 + (((2 * g) ^ (ra & 7)) << 4);
    aoff[i][1] = ra * 128 + (((2 * g + 1) ^ (ra & 7)) << 4);
    woff[i][0] = rb * 128 + (((2 * g) ^ (rb & 7)) << 4);
    woff[i][1] = rb * 128 + (((2 * g + 1) ^ (rb & 7)) << 4);
  }

  vf4 acc[4][4] = {};

  for (int t = 0; t < nkt; ++t) {
    __syncthreads();
#pragma unroll
    for (int c = 0; c < 32; c += 8) {
      __builtin_amdgcn_global_load_lds((const as1void*)(asrc + (size_t)c * K),
                                       (as3void*)(adst + c * 128), 16, 0, 0);
      __builtin_amdgcn_global_load_lds((const as1void*)(wsrc + (size_t)c * K),
                                       (as3void*)(wdst + c * 128), 16, 0, 0);
    }
    asrc += 128;
    wsrc += 128;
    __syncthreads();
    frag8 af[4], wf[4];
#pragma unroll
    for (int i = 0; i < 4; ++i) {
      af[i].h[0] = *(const v4i*)(As + aoff[i][0]);
      af[i].h[1] = *(const v4i*)(As + aoff[i][1]);
      wf[i].h[0] = *(const v4i*)(Ws + woff[i][0]);
      wf[i].h[1] = *(const v4i*)(Ws + woff[i][1]);
    }
#pragma unroll
    for (int mi = 0; mi < 4; ++mi)
#pragma unroll
      for (int ni = 0; ni < 4; ++ni)
        acc[mi][ni] = MFMA_SC(af[mi].w, wf[ni].w, acc[mi][ni]);
  }

  const int rl = g << 2;
  const int rbase = bm * 128 + wr * 64;
  const int cbase = bn * 128 + wc * 64;
#pragma unroll
  for (int mi = 0; mi < 4; ++mi) {
#pragma unroll
    for (int j = 0; j < 4; ++j) {
      const int r = rbase + mi * 16 + rl + j;
      size_t orow;
      if (MODE == 1) {
        int m = r >> 6, t2 = r & 63;
        int b = m / 144, mm = m % 144;
        int wh = mm / 12, ww = mm % 12;
        int h = wh * 8 + (t2 >> 3), w = ww * 8 + (t2 & 7);
        orow = (size_t)((b * 96 + h) * 96 + w);
      } else {
        orow = (size_t)r;
      }
#pragma unroll
      for (int ni = 0; ni < 4; ++ni) {
        const int c = cbase + ni * 16 + cl;
        const float v = acc[mi][ni][j] + bias[c];
        if (MODE == 0) {
          ((uint8_t*)outp)[(size_t)r * ldOut + c] = q8(v);
        } else if (MODE == 1) {
          const float* rx = (const float*)resid;
          ((__hip_bfloat16*)outp)[orow * DIM + c] =
              __float2bfloat16(rx[orow * DIM + c] + lsv[c] * v);
        } else {
          const __hip_bfloat16* rx = (const __hip_bfloat16*)resid;
          ((float*)outp)[(size_t)r * DIM + c] =
              __bfloat162float(rx[(size_t)r * DIM + c]) + lsv[c] * v;
        }
      }
    }
  }
}

// ---------------- GLU fp8 GEMM (R11 core), fp8 h out --------------
__global__ __launch_bounds__(256, 2) void k_gemm_glu(const uint8_t* __restrict__ A8,
                                                     const uint8_t* __restrict__ W8,
                                                     const float* __restrict__ bias,
                                                     uint8_t* __restrict__ hout) {
  __shared__ alignas(16) char As[128 * 128];
  __shared__ alignas(16) char B0s[64 * 128];
  __shared__ alignas(16) char B1s[64 * 128];
  constexpr int K = DIM;
  const int nwg = gridDim.x;
  int bid = blockIdx.x;
  bid = (bid & 7) * (nwg >> 3) + (bid >> 3);
  const int bm = bid / 22, bn = bid % 22;
  const int tid = threadIdx.x, wave = tid >> 6, lane = tid & 63;
  const int wr = wave >> 1, wc = wave & 1;
  const int cl = lane & 15, g = lane >> 4;

  const int ro = lane >> 3, pb = lane & 7;
  const int swz = (pb ^ ro) << 4;
  const int r0a = wave * 32, r0b = wave * 16;
  const uint8_t* asrc = A8 + (size_t)bm * 128 * K + (size_t)(r0a + ro) * K + swz;
  const uint8_t* b0src = W8 + (size_t)(bn * 64 + r0b + ro) * K + swz;
  const uint8_t* b1src = W8 + (size_t)(INNERP + bn * 64 + r0b + ro) * K + swz;
  char* adst = As + r0a * 128;
  char* b0dst = B0s + r0b * 128;
  char* b1dst = B1s + r0b * 128;

  int aoff[4][2], boff[2][2];
#pragma unroll
  for (int i = 0; i < 4; ++i) {
    const int ra = wr * 64 + cl + i * 16;
    aoff[i][0] = ra * 128 + (((2 * g) ^ (ra & 7)) << 4);
    aoff[i][1] = ra * 128 + (((2 * g + 1) ^ (ra & 7)) << 4);
  }
#pragma unroll
  for (int i = 0; i < 2; ++i) {
    const int rb = wc * 32 + cl + i * 16;
    boff[i][0] = rb * 128 + (((2 * g) ^ (rb & 7)) << 4);
    boff[i][1] = rb * 128 + (((2 * g + 1) ^ (rb & 7)) << 4);
  }

  vf4 a0[4][2] = {}, a1[4][2] = {};

#pragma unroll
  for (int t = 0; t < 4; ++t) {
    __syncthreads();
#pragma unroll
    for (int c = 0; c < 32; c += 8)
      __builtin_amdgcn_global_load_lds((const as1void*)(asrc + (size_t)c * K),
                                       (as3void*)(adst + c * 128), 16, 0, 0);
#pragma unroll
    for (int c = 0; c < 16; c += 8) {
      __builtin_amdgcn_global_load_lds((const as1void*)(b0src + (size_t)c * K),
                                       (as3void*)(b0dst + c * 128), 16, 0, 0);
      __builtin_amdgcn_global_load_lds((const as1void*)(b1src + (size_t)c * K),
                                       (as3void*)(b1dst + c * 128), 16, 0, 0);
    }
    asrc += 128;
    b0src += 128;
    b1src += 128;
    __syncthreads();
    frag8 af[4], w0f[2], w1f[2];
#pragma unroll
    for (int i = 0; i < 4; ++i) {
      af[i].h[0] = *(const v4i*)(As + aoff[i][0]);
      af[i].h[1] = *(const v4i*)(As + aoff[i][1]);
    }
#pragma unroll
    for (int i = 0; i < 2; ++i) {
      w0f[i].h[0] = *(const v4i*)(B0s + boff[i][0]);
      w0f[i].h[1] = *(const v4i*)(B0s + boff[i][1]);
      w1f[i].h[0] = *(const v4i*)(B1s + boff[i][0]);
      w1f[i].h[1] = *(const v4i*)(B1s + boff[i][1]);
    }
#pragma unroll
    for (int mi = 0; mi < 4; ++mi)
#pragma unroll
      for (int ni = 0; ni < 2; ++ni) {
        a0[mi][ni] = MFMA_SC(af[mi].w, w0f[ni].w, a0[mi][ni]);
        a1[mi][ni] = MFMA_SC(af[mi].w, w1f[ni].w, a1[mi][ni]);
      }
  }

  const int rl = g << 2;
  const int rbase = bm * 128 + wr * 64;
  const int cbase = bn * 64 + wc * 32;
#pragma unroll
  for (int mi = 0; mi < 4; ++mi)
#pragma unroll
    for (int j = 0; j < 4; ++j) {
      const int r = rbase + mi * 16 + rl + j;
#pragma unroll
      for (int ni = 0; ni < 2; ++ni) {
        const int c = cbase + ni * 16 + cl;
        const float a = a0[mi][ni][j] + bias[c];
        const float gv = a1[mi][ni][j] + bias[INNERP + c];
        const float sg = 1.0f / (1.0f + __expf(-gv));
        hout[(size_t)r * INNERP + c] = q8(a * gv * sg);
      }
    }
}

// ---------------- attention: bf16 MFMA core, fp8 in (reg convert) / fp8 out -----------
__global__ __launch_bounds__(256, 2) void k_attn_mfma(const uint8_t* __restrict__ qkv,
                                                      uint8_t* __restrict__ o) {
  __shared__ __hip_bfloat16 sm[4][6912];
  const int wave = threadIdx.x >> 6, lane = threadIdx.x & 63;
  const int task = blockIdx.x * 4 + wave;
  const int w = task >> 4, hd = task & 15;
  const int g = lane >> 4, c = lane & 15;
  __hip_bfloat16* smp = sm[wave];
  __hip_bfloat16* smv = smp + 4608;

  const uint8_t* base = qkv + (size_t)w * 64 * 1536 + hd * 32;

  vbf8 qf[4], kf[4];
#pragma unroll
  for (int i = 0; i < 4; ++i) {
    const uint8_t* qrow = base + (size_t)(i * 16 + c) * 1536 + g * 8;
    qf[i] = cvt8fp8(*(const uint2*)qrow);
    kf[i] = cvt8fp8(*(const uint2*)(qrow + 512));
  }

  {
    const uint8_t* vrow = base + (size_t)lane * 1536 + 1024;
    union {
      vbf8 v;
      ushort e[8];
    } uv;
#pragma unroll
    for (int i = 0; i < 4; ++i) {
      uv.v = cvt8fp8(*(const uint2*)(vrow + i * 8));
#pragma unroll
      for (int j = 0; j < 8; ++j)
        ((ushort*)smv)[(i * 8 + j) * 72 + lane] = uv.e[j];
    }
  }

  vf4 st[4][4];
#pragma unroll
  for (int iq = 0; iq < 4; ++iq)
#pragma unroll
    for (int it = 0; it < 4; ++it) {
      vf4 z = {};
      st[iq][it] = __builtin_amdgcn_mfma_f32_16x16x32_bf16(qf[iq], kf[it], z, 0, 0, 0);
    }

  float inv[4][4];
#pragma unroll
  for (int iq = 0; iq < 4; ++iq) {
#pragma unroll
    for (int j = 0; j < 4; ++j) {
      float m = fmaxf(fmaxf(st[iq][0][j], st[iq][1][j]), fmaxf(st[iq][2][j], st[iq][3][j]));
      m = fmaxf(m, __shfl_xor(m, 1));
      m = fmaxf(m, __shfl_xor(m, 2));
      m = fmaxf(m, __shfl_xor(m, 4));
      m = fmaxf(m, __shfl_xor(m, 8));
      float s = 0.f;
#pragma unroll
      for (int it = 0; it < 4; ++it) {
        const float e = __expf((st[iq][it][j] - m) * 0.17677669529663687f);
        st[iq][it][j] = e;
        s += e;
      }
      s += __shfl_xor(s, 1);
      s += __shfl_xor(s, 2);
      s += __shfl_xor(s, 4);
      s += __shfl_xor(s, 8);
      inv[iq][j] = 1.0f / s;
    }
  }

#pragma unroll
  for (int iq = 0; iq < 4; ++iq)
#pragma unroll
    for (int j = 0; j < 4; ++j) {
      const int q = iq * 16 + g * 4 + j;
#pragma unroll
      for (int it = 0; it < 4; ++it)
        smp[q * 72 + it * 16 + c] = __float2bfloat16(st[iq][it][j]);
    }

  vf4 ot[4][2] = {};
#pragma unroll
  for (int ks = 0; ks < 2; ++ks) {
    vbf8 pf[4], vfr[2];
#pragma unroll
    for (int iq = 0; iq < 4; ++iq)
      pf[iq] = *(const vbf8*)(smp + (iq * 16 + c) * 72 + ks * 32 + g * 8);
#pragma unroll
    for (int dt = 0; dt < 2; ++dt)
      vfr[dt] = *(const vbf8*)(smv + (dt * 16 + c) * 72 + ks * 32 + g * 8);
#pragma unroll
    for (int iq = 0; iq < 4; ++iq)
#pragma unroll
      for (int dt = 0; dt < 2; ++dt)
        ot[iq][dt] = __builtin_amdgcn_mfma_f32_16x16x32_bf16(pf[iq], vfr[dt], ot[iq][dt], 0, 0, 0);
  }

#pragma unroll
  for (int iq = 0; iq < 4; ++iq)
#pragma unroll
    for (int dt = 0; dt < 2; ++dt)
#pragma unroll
      for (int j = 0; j < 4; ++j) {
        const int q = iq * 16 + g * 4 + j;
        smp[q * 72 + dt * 16 + c] = __float2bfloat16(ot[iq][dt][j] * inv[iq][j]);
      }
  uint8_t* ob = o + (size_t)w * 64 * 512 + hd * 32;
#pragma unroll
  for (int i = 0; i < 4; ++i) {
    const int idx = i * 64 + lane;
    const int row = idx >> 2, chunk = idx & 3;
    union {
      vbf8 v;
      ushort e[8];
    } u;
    u.v = *(const vbf8*)(smp + row * 72 + chunk * 8);
    float f[8];
#pragma unroll
    for (int j = 0; j < 8; ++j) f[j] = __uint_as_float((unsigned)u.e[j] << 16);
    uint2 pv;
    pv.x = pk4fp8(f[0], f[1], f[2], f[3]);
    pv.y = pk4fp8(f[4], f[5], f[6], f[7]);
    *(uint2*)(ob + (size_t)row * 512 + chunk * 8) = pv;
  }
}

// ---------------- launch ----------------
extern "C" void kernel_launch(void* const* d_in, const int* in_sizes, int n_in, void* d_out,
                              int out_size, void* d_ws, size_t ws_size, hipStream_t stream) {
  const float* x = (const float*)d_in[0];
  const float* n1g = (const float*)d_in[1];
  const float* n1b = (const float*)d_in[2];
  const float* qkv_w = (const float*)d_in[3];
  const float* qkv_b = (const float*)d_in[4];
  const float* proj_w = (const float*)d_in[5];
  const float* proj_b = (const float*)d_in[6];
  const float* ls1 = (const float*)d_in[7];
  const float* n2g = (const float*)d_in[8];
  const float* n2b = (const float*)d_in[9];
  const float* glu_w = (const float*)d_in[10];
  const float* glu_b = (const float*)d_in[11];
  const float* fc2_w = (const float*)d_in[12];
  const float* fc2_b = (const float*)d_in[13];
  const float* ls2 = (const float*)d_in[14];

  if (ws_size < 268000000u) return;

  char* ws = (char*)d_ws;
  uint8_t* wTq = (uint8_t*)(ws + 0);            // [1536][512] fp8
  uint8_t* wTp = (uint8_t*)(ws + 786432);       // [512][512]
  uint8_t* wTg = (uint8_t*)(ws + 1048576);      // [2816][512] padded
  uint8_t* wTf = (uint8_t*)(ws + 2490368);      // [512][1408] padded
  float* gbias = (float*)(ws + 3211264);        // [2816]
  uint8_t* act8 = (uint8_t*)(ws + 3222528);     // [73728][512] fp8 (y1 -> o -> y2)
  char* big = ws + 40971264;
  uint8_t* qkv8 = (uint8_t*)big;                // [73728][1536] fp8 (113 MB)
  uint8_t* h8 = (uint8_t*)big;                  // [73728][1408] fp8 (alias, dead qkv)
  __hip_bfloat16* x1b = (__hip_bfloat16*)(big + 113246208);  // [73728][512] bf16

  hipMemsetAsync(wTg, 0, 1441792, stream);
  hipMemsetAsync(wTf, 0, 720896, stream);

  dim3 tb(32, 8);
  k_transpose<<<dim3(48, 16), tb, 0, stream>>>(qkv_w, wTq, 512, 1536, 512, 1 << 30);
  k_transpose<<<dim3(16, 16), tb, 0, stream>>>(proj_w, wTp, 512, 512, 512, 1 << 30);
  k_transpose<<<dim3(84, 16), tb, 0, stream>>>(glu_w, wTg, 512, 2688, 512, INNER);
  k_transpose<<<dim3(16, 42), tb, 0, stream>>>(fc2_w, wTf, 1344, 512, 1408, 1 << 30);
  k_padbias<<<11, 256, 0, stream>>>(glu_b, gbias);

  k_ln<true, false><<<18432, 256, 0, stream>>>(x, n1g, n1b, act8);
  k_gemm128<512, 0, 12><<<6912, 256, 0, stream>>>(act8, wTq, qkv_b, qkv8, nullptr, nullptr, 1536);
  k_attn_mfma<<<4608, 256, 0, stream>>>(qkv8, act8);
  k_gemm128<512, 1, 4><<<2304, 256, 0, stream>>>(act8, wTp, proj_b, (void*)x1b, x, ls1, 512);
  k_ln<false, true><<<18432, 256, 0, stream>>>(x1b, n2g, n2b, act8);
  k_gemm_glu<<<12672, 256, 0, stream>>>(act8, wTg, gbias, h8);
  k_gemm128<1408, 2, 4><<<2304, 256, 0, stream>>>(h8, wTf, fc2_b, d_out, x1b, ls2, 512);
}